// Round 1
// baseline (207.514 us; speedup 1.0000x reference)
//
#include <hip/hip_runtime.h>

#define D_ 160
#define H_ 192
#define W_ 160
#define PLANE (H_*W_)          // 30720
#define VOL (D_*PLANE)         // 4915200 per sample
#define NS 2
#define R_ 4                   // window radius (win=9)
#define WSZ 729.0f

// ---------------- zero the two accumulators ----------------
__global__ void k_zero(float* acc) {
    if (threadIdx.x < NS) acc[threadIdx.x] = 0.f;
}

// ---------------- pass 1: products + W-axis 9-box-sum ----------------
// 8 outputs per thread along w; 20 segments per row; rows = D_*H_ = 30720/sample
// tasks = 30720*20 = 614400 -> 2400 blocks of 256
__global__ __launch_bounds__(256) void k_w(const float* __restrict__ I,
                                           const float* __restrict__ J,
                                           float* __restrict__ A, int s) {
    int t   = blockIdx.x * 256 + threadIdx.x;
    int seg = t % 20;
    int r   = t / 20;                       // local row 0..30719
    long gbase = ((long)s * 30720 + r) * W_;
    long lbase = (long)r * W_;
    int w0 = seg * 8;

    // load taps w0-4 .. w0+11 (16 values), zero-padded, as 4 aligned float4s
    float vI[16], vJ[16];
#pragma unroll
    for (int b = 0; b < 4; ++b) {
        int f0 = w0 - 4 + 4 * b;            // multiple of 4 -> 16B aligned
        if (f0 >= 0 && f0 <= W_ - 4) {
            float4 a = *reinterpret_cast<const float4*>(I + gbase + f0);
            float4 c = *reinterpret_cast<const float4*>(J + gbase + f0);
            vI[4*b+0]=a.x; vI[4*b+1]=a.y; vI[4*b+2]=a.z; vI[4*b+3]=a.w;
            vJ[4*b+0]=c.x; vJ[4*b+1]=c.y; vJ[4*b+2]=c.z; vJ[4*b+3]=c.w;
        } else {
#pragma unroll
            for (int k = 0; k < 4; ++k) { vI[4*b+k] = 0.f; vJ[4*b+k] = 0.f; }
        }
    }

    // quantities: 0:I 1:J 2:I*I 3:J*J 4:I*J
#pragma unroll
    for (int q = 0; q < 5; ++q) {
        float p[16];
#pragma unroll
        for (int i = 0; i < 16; ++i) {
            float a = vI[i], b = vJ[i];
            p[i] = (q == 0) ? a : (q == 1) ? b : (q == 2) ? a*a : (q == 3) ? b*b : a*b;
        }
        float o[8];
        float ssum = 0.f;
#pragma unroll
        for (int i = 0; i < 9; ++i) ssum += p[i];
        o[0] = ssum;
#pragma unroll
        for (int k = 1; k < 8; ++k) { ssum += p[k + 8] - p[k - 1]; o[k] = ssum; }

        float* outp = A + (long)q * VOL + lbase + w0;
        *reinterpret_cast<float4*>(outp)     = make_float4(o[0], o[1], o[2], o[3]);
        *reinterpret_cast<float4*>(outp + 4) = make_float4(o[4], o[5], o[6], o[7]);
    }
}

// ---------------- pass 2: H-axis 9-box-sum, IN PLACE ----------------
// one thread per (quantity, d, w) column: 5*160*160 = 128000 -> 500 blocks
// in-place is safe: each column owned by one thread; raw values live in the ring
__global__ __launch_bounds__(256) void k_h(float* __restrict__ A) {
    int t = blockIdx.x * 256 + threadIdx.x;   // 0..127999
    int q = t / 25600;
    int c = t % 25600;
    int w = c % W_;
    int d = c / W_;
    float* base = A + (long)q * VOL + (long)d * PLANE + w;   // [h] -> base[h*W_]

    float win[9];
    float sum = 0.f;
#pragma unroll
    for (int i = 0; i < 9; ++i) {
        int h = i - R_;
        float v = (h >= 0) ? base[h * W_] : 0.f;   // h<=4 < 192 always valid
        win[i] = v; sum += v;
    }
    for (int h = 0; h < H_; ++h) {
        float nv = (h + 5 < H_) ? base[(h + 5) * W_] : 0.f;
        base[h * W_] = sum;                        // output h (in place)
        sum += nv - win[0];
#pragma unroll
        for (int i = 0; i < 8; ++i) win[i] = win[i + 1];
        win[8] = nv;
    }
}

// ---------------- pass 3: D-axis 9-box-sum + cc + reduction ----------------
// one thread per (h,w) column x 4 d-chunks of 40: 30720*4 = 122880 -> 480 blocks
__global__ __launch_bounds__(256) void k_d(const float* __restrict__ A,
                                           float* __restrict__ acc, int s) {
    int t     = blockIdx.x * 256 + threadIdx.x;   // 0..122879
    int col   = t % 30720;
    int chunk = t / 30720;                        // 0..3
    int w = col % W_;
    int h = col / W_;
    int d0 = chunk * 40;
    const float* base = A + (long)h * W_ + w;     // + q*VOL + d*PLANE

    float win[5][9], sum[5];
#pragma unroll
    for (int q = 0; q < 5; ++q) {
        sum[q] = 0.f;
#pragma unroll
        for (int i = 0; i < 9; ++i) {
            int d = d0 + i - R_;
            float v = (d >= 0 && d < D_) ? base[(long)q * VOL + (long)d * PLANE] : 0.f;
            win[q][i] = v; sum[q] += v;
        }
    }

    float local = 0.f;
    for (int dd = 0; dd < 40; ++dd) {
        float Is = sum[0], Js = sum[1], I2 = sum[2], J2 = sum[3], IJ = sum[4];
        float uI = Is * (1.f / WSZ), uJ = Js * (1.f / WSZ);
        float cross = IJ - uJ * Is - uI * Js + uI * uJ * WSZ;
        float Iv = I2 - 2.f * uI * Is + uI * uI * WSZ;
        float Jv = J2 - 2.f * uJ * Js + uJ * uJ * WSZ;
        float cc = 1.f - cross * cross / (Iv * Jv + 1e-5f);
        local += cc;

        int dn = d0 + dd + 5;
#pragma unroll
        for (int q = 0; q < 5; ++q) {
            float nv = (dn < D_) ? base[(long)q * VOL + (long)dn * PLANE] : 0.f;
            sum[q] += nv - win[q][0];
#pragma unroll
            for (int i = 0; i < 8; ++i) win[q][i] = win[q][i + 1];
            win[q][8] = nv;
        }
    }

    __shared__ float red[256];
    red[threadIdx.x] = local;
    __syncthreads();
    for (int off = 128; off > 0; off >>= 1) {
        if (threadIdx.x < off) red[threadIdx.x] += red[threadIdx.x + off];
        __syncthreads();
    }
    if (threadIdx.x == 0) atomicAdd(acc + s, red[0]);
}

// ---------------- finalize ----------------
__global__ void k_fin(const float* __restrict__ acc, float* __restrict__ out) {
    if (threadIdx.x < NS) out[threadIdx.x] = acc[threadIdx.x] * (1.f / (float)VOL);
}

extern "C" void kernel_launch(void* const* d_in, const int* in_sizes, int n_in,
                              void* d_out, int out_size, void* d_ws, size_t ws_size,
                              hipStream_t stream) {
    const float* J = (const float*)d_in[0];   // y_pred
    const float* I = (const float*)d_in[1];   // y_true
    float* out = (float*)d_out;
    float* A   = (float*)d_ws;                // 5 * VOL floats (per-sample, reused)
    float* acc = A + 5L * VOL;                // 2 floats

    k_zero<<<1, 64, 0, stream>>>(acc);
    for (int s = 0; s < NS; ++s) {
        k_w<<<2400, 256, 0, stream>>>(I, J, A, s);
        k_h<<<500,  256, 0, stream>>>(A);
        k_d<<<480,  256, 0, stream>>>(A, acc, s);
    }
    k_fin<<<1, 64, 0, stream>>>(acc, out);
}

// Round 2
// 168.241 us; speedup vs baseline: 1.2334x; 1.2334x over previous
//
#include <hip/hip_runtime.h>
#include <hip/hip_fp16.h>

#define D_ 160
#define H_ 192
#define W_ 160
#define PLANE (H_*W_)          // 30720
#define VOL (D_*PLANE)         // 4915200 per sample
#define NS 2
#define WSZ 729.0f

// A/B arrays: 5 quantities (I, J, I*I, J*J, I*J), each VOL fp16, layout [q][d][h][w]

// ---------------- zero accumulators ----------------
__global__ void k_zero(float* acc) {
    if (threadIdx.x < NS) acc[threadIdx.x] = 0.f;
}

// ---------------- pass 1: products + W-axis 9-box-sum -> fp16 A ----------------
// 8 outputs/thread along w; 20 segments/row; rows = D_*H_ = 30720/sample
// grid per sample: 2400 blocks of 256
__global__ __launch_bounds__(256) void k_w(const float* __restrict__ I,
                                           const float* __restrict__ J,
                                           __half* __restrict__ A,
                                           int s0, long Astride) {
    int b  = blockIdx.x;
    int sl = b / 2400;
    int t  = (b % 2400) * 256 + threadIdx.x;
    int s  = s0 + sl;
    int seg = t % 20;
    int r   = t / 20;                       // d*H_ + h, 0..30719
    long gbase = ((long)s * 30720 + r) * W_;
    long lbase = (long)r * W_;
    int w0 = seg * 8;
    __half* As = A + sl * Astride;

    // taps w0-4 .. w0+11 (16 values), zero-padded, 4 aligned float4s
    float vI[16], vJ[16];
#pragma unroll
    for (int bq = 0; bq < 4; ++bq) {
        int f0 = w0 - 4 + 4 * bq;           // multiple of 4 -> 16B aligned
        if (f0 >= 0 && f0 <= W_ - 4) {
            float4 a = *reinterpret_cast<const float4*>(I + gbase + f0);
            float4 c = *reinterpret_cast<const float4*>(J + gbase + f0);
            vI[4*bq+0]=a.x; vI[4*bq+1]=a.y; vI[4*bq+2]=a.z; vI[4*bq+3]=a.w;
            vJ[4*bq+0]=c.x; vJ[4*bq+1]=c.y; vJ[4*bq+2]=c.z; vJ[4*bq+3]=c.w;
        } else {
#pragma unroll
            for (int k = 0; k < 4; ++k) { vI[4*bq+k] = 0.f; vJ[4*bq+k] = 0.f; }
        }
    }

#pragma unroll
    for (int q = 0; q < 5; ++q) {
        float p[16];
#pragma unroll
        for (int i = 0; i < 16; ++i) {
            float a = vI[i], bb = vJ[i];
            p[i] = (q == 0) ? a : (q == 1) ? bb : (q == 2) ? a*a : (q == 3) ? bb*bb : a*bb;
        }
        float o[8];
        float ssum = 0.f;
#pragma unroll
        for (int i = 0; i < 9; ++i) ssum += p[i];
        o[0] = ssum;
#pragma unroll
        for (int k = 1; k < 8; ++k) { ssum += p[k + 8] - p[k - 1]; o[k] = ssum; }

        union U { __half h[8]; int4 v; } u;
#pragma unroll
        for (int k = 0; k < 8; ++k) u.h[k] = __float2half(o[k]);
        __half* outp = As + (long)q * VOL + lbase + w0;
        *reinterpret_cast<int4*>(outp) = u.v;   // 16B store
    }
}

// ---------------- pass 2: H-axis 9-box-sum, fp16 A -> fp16 B ----------------
// w-pairs (__half2), 4 h-chunks of 48 (8-row halo re-read), out-of-place
// threads/sample: wp(80) x chunk(4) x d(160) x q(5) = 256000 -> 1000 blocks
__global__ __launch_bounds__(256) void k_h(const __half* __restrict__ P, long stride) {
    int b  = blockIdx.x;
    int sl = b / 1000;
    int t  = (b % 1000) * 256 + threadIdx.x;    // 0..255999
    int wp    = t % 80;
    int chunk = (t / 80) % 4;
    int d     = (t / 320) % 160;
    int q     = t / 51200;
    int h0 = chunk * 48;
    long base = (long)q * VOL + (long)d * PLANE + 2 * wp;
    const __half* Ab = P + (long)sl * stride + base;
    __half*       Bb = const_cast<__half*>(P) + (long)sl * stride + 5L * VOL + base;

    float2 ring[9];
#pragma unroll
    for (int i = 0; i < 9; ++i) ring[i] = make_float2(0.f, 0.f);
    float sx = 0.f, sy = 0.f;

    for (int i = 0; i < 56; ++i) {
        int h_in = h0 - 4 + i;
        float2 v = make_float2(0.f, 0.f);
        if (h_in >= 0 && h_in < H_) {
            __half2 hv = *reinterpret_cast<const __half2*>(Ab + (long)h_in * W_);
            v = __half22float2(hv);
        }
        sx += v.x - ring[0].x;
        sy += v.y - ring[0].y;
#pragma unroll
        for (int k = 0; k < 8; ++k) ring[k] = ring[k + 1];
        ring[8] = v;
        if (i >= 8) {
            int h_out = h_in - 4;
            *reinterpret_cast<__half2*>(Bb + (long)h_out * W_) = __floats2half2_rn(sx, sy);
        }
    }
}

// ---------------- pass 3: D-axis 9-box-sum + cc + reduction ----------------
// one thread per (h,w) column x 4 d-chunks of 40: 122880/sample -> 480 blocks
__global__ __launch_bounds__(256) void k_d(const __half* __restrict__ B,
                                           float* __restrict__ acc, int s0, long stride) {
    int sl = blockIdx.x / 480;
    int t  = (blockIdx.x % 480) * 256 + threadIdx.x;   // 0..122879
    const __half* Bs = B + (long)sl * stride;
    int col   = t % 30720;
    int chunk = t / 30720;                        // 0..3
    int w = col % W_;
    int h = col / W_;
    int d0 = chunk * 40;
    const __half* base = Bs + (long)h * W_ + w;   // + q*VOL + d*PLANE

    float win[5][9], sum[5];
#pragma unroll
    for (int q = 0; q < 5; ++q) {
        sum[q] = 0.f;
#pragma unroll
        for (int i = 0; i < 9; ++i) {
            int d = d0 + i - 4;
            float v = (d >= 0 && d < D_) ? __half2float(base[(long)q * VOL + (long)d * PLANE]) : 0.f;
            win[q][i] = v; sum[q] += v;
        }
    }

    float local = 0.f;
    for (int dd = 0; dd < 40; ++dd) {
        float Is = sum[0], Js = sum[1], I2 = sum[2], J2 = sum[3], IJ = sum[4];
        float uI = Is * (1.f / WSZ), uJ = Js * (1.f / WSZ);
        float cross = IJ - uJ * Is - uI * Js + uI * uJ * WSZ;
        float Iv = I2 - 2.f * uI * Is + uI * uI * WSZ;
        float Jv = J2 - 2.f * uJ * Js + uJ * uJ * WSZ;
        float cc = 1.f - cross * cross / (Iv * Jv + 1e-5f);
        local += cc;

        int dn = d0 + dd + 5;
#pragma unroll
        for (int q = 0; q < 5; ++q) {
            float nv = (dn < D_) ? __half2float(base[(long)q * VOL + (long)dn * PLANE]) : 0.f;
            sum[q] += nv - win[q][0];
#pragma unroll
            for (int i = 0; i < 8; ++i) win[q][i] = win[q][i + 1];
            win[q][8] = nv;
        }
    }

    __shared__ float red[256];
    red[threadIdx.x] = local;
    __syncthreads();
    for (int off = 128; off > 0; off >>= 1) {
        if (threadIdx.x < off) red[threadIdx.x] += red[threadIdx.x + off];
        __syncthreads();
    }
    if (threadIdx.x == 0) atomicAdd(acc + s0 + sl, red[0]);
}

// ---------------- finalize ----------------
__global__ void k_fin(const float* __restrict__ acc, float* __restrict__ out) {
    if (threadIdx.x < NS) out[threadIdx.x] = acc[threadIdx.x] * (1.f / (float)VOL);
}

extern "C" void kernel_launch(void* const* d_in, const int* in_sizes, int n_in,
                              void* d_out, int out_size, void* d_ws, size_t ws_size,
                              hipStream_t stream) {
    const float* J = (const float*)d_in[0];   // y_pred
    const float* I = (const float*)d_in[1];   // y_true
    float* out = (float*)d_out;
    __half* W  = (__half*)d_ws;

    const long SAMP = 10L * VOL;              // elements (A + B) per sample, fp16
    size_t bat_need = (size_t)(2 * SAMP) * sizeof(__half) + 8;
    size_t seq_need = (size_t)SAMP * sizeof(__half) + 8;

    if (ws_size >= bat_need) {
        // layout: [A0 B0 | A1 B1 | acc]
        float* acc = (float*)((char*)d_ws + (size_t)(2 * SAMP) * sizeof(__half));
        k_zero<<<1, 64, 0, stream>>>(acc);
        k_w<<<2 * 2400, 256, 0, stream>>>(I, J, W, 0, SAMP);
        k_h<<<2 * 1000, 256, 0, stream>>>(W, SAMP);
        k_d<<<2 * 480,  256, 0, stream>>>(W + 5L * VOL, acc, 0, SAMP);
        k_fin<<<1, 64, 0, stream>>>(acc, out);
    } else {
        (void)seq_need; // known to fit: 98,304,008 bytes
        float* acc = (float*)((char*)d_ws + (size_t)SAMP * sizeof(__half));
        k_zero<<<1, 64, 0, stream>>>(acc);
        for (int s = 0; s < NS; ++s) {
            k_w<<<2400, 256, 0, stream>>>(I, J, W, s, 0);
            k_h<<<1000, 256, 0, stream>>>(W, 0);
            k_d<<<480,  256, 0, stream>>>(W + 5L * VOL, acc, s, 0);
        }
        k_fin<<<1, 64, 0, stream>>>(acc, out);
    }
}